// Round 1
// baseline (188.412 us; speedup 1.0000x reference)
//
#include <hip/hip_runtime.h>

#define DIM   128
#define CPT   256         // chars per wave-chunk
#define TAIL  64          // staged lookahead for cross-chunk tails
#define WPB   4           // waves per block
#define QD    40          // per-wave boundary head-id queue depth (Poisson(16) tail-safe)

// out = N - <H,T>_F / (||H||_F ||T||_F).  T never materialized.
// Full-row layout: lane owns 2 columns (float2, 8 B/lane -> 512 B/row coalesced).
// All 64 lanes process the SAME char together -> wave-uniform control flow.
// Segment boundaries precomputed as 64-bit ballot masks in SGPRs (scalar bit
// test per char). NEW vs prev version: (a) one slice instead of two (halves
// gathers, staging, ballots, ids traffic, boundary events), (b) per-boundary
// head ids pre-gathered into an LDS queue during staging, prefetched one
// segment ahead -> the flush path has a single load in its chain (row value)
// instead of id-fetch -> row-fetch.
__global__ __launch_bounds__(256) void fused_kernel(
    const float* __restrict__ char_emb,
    const float* __restrict__ ent,
    const int* __restrict__ head_ids,
    const int* __restrict__ char_ids,
    const int* __restrict__ seg_ids,
    float* __restrict__ pb,        // [gridDim.x*3] block partials: ht,tt,hh
    int total_chars, int n_triples, int hh_per_block)
{
    __shared__ __align__(16) int s_off[WPB][CPT + TAIL];  // cid<<9 (row byte off)
    __shared__ int s_sid[WPB][CPT + TAIL];
    __shared__ int s_hq[WPB][QD];                         // boundary head ids
    __shared__ float r_scr[3][WPB];

    const int tid  = threadIdx.x;
    const int lane = tid & 63;
    const int wid  = tid >> 6;
    const int colb = lane << 3;               // byte offset of lane's float2

    float ht = 0.f, tt = 0.f, hh = 0.f;

    const int chunk = blockIdx.x * WPB + wid;
    const int start = chunk * CPT;
    const int len   = min(CPT, total_chars - start);
    const int sl    = min(CPT + TAIL, total_chars - start);
    const char* cb  = (const char*)char_emb;
    const float* ee = ent + (lane << 1);      // lane's 2 columns of ent rows

    // ---- stage offsets + sids (wave-local region) ----
    for (int c = lane; c < sl; c += 64) {
        s_off[wid][c] = char_ids[start + c] << 9;
        s_sid[wid][c] = seg_ids[start + c];
    }

    // ---- boundary masks (SGPR) + head-id queue build (rank = prefix popcount)
    unsigned long long mk[4] = {0ull, 0ull, 0ull, 0ull};
    if (len == CPT) {
        int rbase = 0;
#pragma unroll
        for (int grp = 0; grp < 4; ++grp) {
            const int cc = grp * 64 + lane;
            const int s1 = s_sid[wid][cc];            // same-wave staged, lgkm-ordered
            const int ip = (cc > 0) ? cc - 1 : 0;
            int s0 = s_sid[wid][ip];
            if (cc == 0) s0 = (start > 0) ? seg_ids[start - 1] : s1 + 1; // char 0: boundary
            const bool bnd = (s1 != s0);
            mk[grp] = __ballot(bnd);
            const int rk = rbase + (int)__popcll(mk[grp] & ((1ull << lane) - 1ull));
            if (bnd && rk < QD) s_hq[wid][rk] = head_ids[s1];  // pre-gather head id
            rbase += (int)__popcll(mk[grp]);
        }
    }
    __syncthreads();

    if (len == CPT) {
        // -------- fast path --------
        int cur = 0;
        float2 hv;  hv.x = 0.f;  hv.y = 0.f;
        float2 acc; acc.x = 0.f; acc.y = 0.f;
        bool live = false;      // first flush dropped iff chunk starts mid-segment
        int rk = 0;
        int nhid = __builtin_amdgcn_readfirstlane(s_hq[wid][0]); // 1-ahead prefetch
        float2 vA[16], vB[16];

#define PF(BUF, B) { \
    _Pragma("unroll") \
    for (int q = 0; q < 4; ++q) { \
        const int4 o4 = *(const int4*)&s_off[wid][(B) * 16 + q * 4]; \
        BUF[q * 4 + 0] = *(const float2*)(cb + (size_t)(unsigned)(o4.x + colb)); \
        BUF[q * 4 + 1] = *(const float2*)(cb + (size_t)(unsigned)(o4.y + colb)); \
        BUF[q * 4 + 2] = *(const float2*)(cb + (size_t)(unsigned)(o4.z + colb)); \
        BUF[q * 4 + 3] = *(const float2*)(cb + (size_t)(unsigned)(o4.w + colb)); \
    } }

#define CS(BUF, B) { \
    _Pragma("unroll") \
    for (int j = 0; j < 16; ++j) { \
        if (mk[(B) >> 2] & (1ull << (((B) & 3) * 16 + j))) {   /* scalar bit test */ \
            if (live) { \
                ht = fmaf(hv.x, acc.x, ht); ht = fmaf(hv.y, acc.y, ht); \
                tt = fmaf(acc.x, acc.x, tt); tt = fmaf(acc.y, acc.y, tt); \
            } \
            live = true; \
            acc.x = 0.f; acc.y = 0.f; \
            cur = __builtin_amdgcn_readfirstlane(s_sid[wid][(B) * 16 + j]); \
            const int hid = (rk < QD) ? nhid : head_ids[cur];  /* queue hit: no id chase */ \
            hv = *(const float2*)(ee + (size_t)hid * DIM); \
            ++rk; \
            nhid = __builtin_amdgcn_readfirstlane(s_hq[wid][rk < QD ? rk : QD - 1]); \
        } \
        acc.x += BUF[j].x; acc.y += BUF[j].y; \
    } }

        PF(vA, 0)
#pragma unroll
        for (int B = 0; B < 16; ++B) {
            if (B + 1 < 16) { if (B & 1) { PF(vA, B + 1) } else { PF(vB, B + 1) } }
            if (B & 1) { CS(vB, B) } else { CS(vA, B) }
        }

        if (live) {
            // tail: last owned segment may continue past chunk end
            int e = CPT;
            bool ended = false;
            while (e < sl) {
                const int idx = e + lane;
                const bool differ = (idx < sl) && (s_sid[wid][idx] != cur);
                const unsigned long long bm = __ballot(differ);
                const int run = bm ? (__ffsll((long long)bm) - 1)
                                   : min(64, sl - e);
                for (int j = 0; j < run; j += 4) {
                    const int mm2 = min(4, run - j);
                    float2 vv[4];
#pragma unroll
                    for (int k = 0; k < 4; ++k) {
                        if (k < mm2)
                            vv[k] = *(const float2*)(cb +
                                (size_t)(unsigned)(s_off[wid][e + j + k] + colb));
                    }
                    for (int k = 0; k < mm2; ++k) { acc.x += vv[k].x; acc.y += vv[k].y; }
                }
                e += run;
                if (bm) { ended = true; break; }
            }
            if (!ended && start + sl < total_chars) {
                int gg = start + sl;                 // very rare long run
                while (gg < total_chars && seg_ids[gg] == cur) {
                    const float2 v = *(const float2*)(cb +
                        (size_t)(unsigned)((char_ids[gg] << 9) + colb));
                    acc.x += v.x; acc.y += v.y;
                    ++gg;
                }
            }
            // final flush
            ht = fmaf(hv.x, acc.x, ht); ht = fmaf(hv.y, acc.y, ht);
            tt = fmaf(acc.x, acc.x, tt); tt = fmaf(acc.y, acc.y, tt);
        }
    } else if (len > 0) {
        // -------- rare fallback (partial last chunk): per char --------
        int p = 0;
        if (start > 0) {
            const int prev = seg_ids[start - 1];
            while (p < len && seg_ids[start + p] == prev) ++p;
        }
        if (p < len) {
            int cur2 = seg_ids[start + p];
            float2 acc; acc.x = 0.f; acc.y = 0.f;
            float2 hv = *(const float2*)(ee + (size_t)head_ids[cur2] * DIM);
            for (int c = p; c < len; ++c) {
                const int sid = seg_ids[start + c];
                if (sid != cur2) {
                    ht += hv.x * acc.x + hv.y * acc.y;
                    tt += acc.x * acc.x + acc.y * acc.y;
                    acc.x = 0.f; acc.y = 0.f; cur2 = sid;
                    hv = *(const float2*)(ee + (size_t)head_ids[cur2] * DIM);
                }
                const float2 v = *(const float2*)(cb +
                    (size_t)(unsigned)((char_ids[start + c] << 9) + colb));
                acc.x += v.x; acc.y += v.y;
            }
            int gg = start + len;
            while (gg < total_chars && seg_ids[gg] == cur2) {
                const float2 v = *(const float2*)(cb +
                    (size_t)(unsigned)((char_ids[gg] << 9) + colb));
                acc.x += v.x; acc.y += v.y;
                ++gg;
            }
            ht += hv.x * acc.x + hv.y * acc.y;
            tt += acc.x * acc.x + acc.y * acc.y;
        }
    }

    // -------- hh strip for this block (covers empty segments exactly) --------
    {
        const float4* e4 = (const float4*)ent;
        const long base = (long)blockIdx.x * hh_per_block * 32;
        const long lim  = (long)n_triples * 32;
        for (int s = tid; s < hh_per_block * 32; s += 256) {
            const long f = base + s;
            if (f < lim) {
                const int row = (int)(f >> 5);
                const int hid = head_ids[row];
                const float4 v = e4[(size_t)hid * 32 + (int)(f & 31)];
                hh += v.x * v.x + v.y * v.y + v.z * v.z + v.w * v.w;
            }
        }
    }

    // -------- block reduce -> per-block partials (no atomics, no memset) ----
#pragma unroll
    for (int off = 32; off > 0; off >>= 1) {
        ht += __shfl_down(ht, off);
        tt += __shfl_down(tt, off);
        hh += __shfl_down(hh, off);
    }
    if (lane == 0) { r_scr[0][wid] = ht; r_scr[1][wid] = tt; r_scr[2][wid] = hh; }
    __syncthreads();
    if (tid == 0) {
        float a = 0.f, b = 0.f, c = 0.f;
#pragma unroll
        for (int w = 0; w < WPB; ++w) {
            a += r_scr[0][w]; b += r_scr[1][w]; c += r_scr[2][w];
        }
        pb[blockIdx.x * 3 + 0] = a;
        pb[blockIdx.x * 3 + 1] = b;
        pb[blockIdx.x * 3 + 2] = c;
    }
}

// final reduce: sums partials in double, writes N - ht/sqrt(hh*tt)
__global__ __launch_bounds__(256) void reduce_kernel(
    const float* __restrict__ pb, int nb, float* __restrict__ out,
    int n_triples)
{
    double ht = 0.0, tt = 0.0, hh = 0.0;
    for (int i = threadIdx.x; i < nb; i += 256) {
        ht += (double)pb[i * 3 + 0];
        tt += (double)pb[i * 3 + 1];
        hh += (double)pb[i * 3 + 2];
    }
#pragma unroll
    for (int off = 32; off > 0; off >>= 1) {
        ht += __shfl_down(ht, off);
        tt += __shfl_down(tt, off);
        hh += __shfl_down(hh, off);
    }
    __shared__ double sd[3][4];
    const int wid = threadIdx.x >> 6;
    if ((threadIdx.x & 63) == 0) { sd[0][wid] = ht; sd[1][wid] = tt; sd[2][wid] = hh; }
    __syncthreads();
    if (threadIdx.x == 0) {
        double a = 0.0, b = 0.0, c = 0.0;
        for (int w = 0; w < 4; ++w) { a += sd[0][w]; b += sd[1][w]; c += sd[2][w]; }
        out[0] = (float)((double)n_triples - a / sqrt(c * b));
    }
}

extern "C" void kernel_launch(void* const* d_in, const int* in_sizes, int n_in,
                              void* d_out, int out_size, void* d_ws, size_t ws_size,
                              hipStream_t stream)
{
    const float* char_emb = (const float*)d_in[0];
    const float* ent_emb  = (const float*)d_in[1];
    const int* head_ids   = (const int*)d_in[2];
    const int* char_ids   = (const int*)d_in[3];
    const int* seg_ids    = (const int*)d_in[4];
    const int n_triples   = in_sizes[2];
    const int total_chars = in_sizes[3];

    const int n_chunks = (total_chars + CPT - 1) / CPT;
    const int nsb = (n_chunks + WPB - 1) / WPB;    // one full-row pass
    const int hhpb = (n_triples + nsb - 1) / nsb;

    float* pb = (float*)d_ws;                      // nsb*3 floats

    fused_kernel<<<nsb, 256, 0, stream>>>(char_emb, ent_emb, head_ids,
                                          char_ids, seg_ids, pb,
                                          total_chars, n_triples, hhpb);
    reduce_kernel<<<1, 256, 0, stream>>>(pb, nsb, (float*)d_out, n_triples);
}

// Round 2
// 186.680 us; speedup vs baseline: 1.0093x; 1.0093x over previous
//
#include <hip/hip_runtime.h>

#define DIM   128
#define HALF  64          // columns per slice (2 slices, XCD-parity L2 residency)
#define CPT   256         // chars per wave-chunk
#define TAIL  64          // staged lookahead for cross-chunk tails
#define WPB   4           // waves per block
#define QD    24          // boundary queue depth (Poisson(16); overflow -> chained path)

// out = N - <H,T>_F / (||H||_F ||T||_F).  T never materialized; hh folded into
// the boundary path (each non-empty segment has exactly one global boundary
// event), empty segments via gap loops + reduce-kernel ends. Wave layout:
// lane = column of the 64-col slice; all lanes process the SAME char together
// -> wave-uniform control flow. Boundary masks are SGPR ballots (scalar bit
// test per char). Head rows for all boundaries in the chunk are pre-gathered
// (4-deep batched, coalesced 256B) into s_hv during setup -> the per-boundary
// critical path in the main loop is one pipelined LDS read, no VMEM chase.
__global__ __launch_bounds__(256) void fused_kernel(
    const float* __restrict__ char_emb,
    const float* __restrict__ ent,
    const int* __restrict__ head_ids,
    const int* __restrict__ char_ids,
    const int* __restrict__ seg_ids,
    float* __restrict__ pb,        // [gridDim.x*3] block partials: ht,tt,hh
    int total_chars, int n_triples)
{
    __shared__ __align__(16) int s_off[WPB][CPT + TAIL];  // (cid<<9)+sco
    __shared__ int s_sid[WPB][CPT + TAIL];
    __shared__ __align__(16) int s_hq[WPB][QD];           // boundary head ids
    __shared__ float s_hv[WPB][QD][64];                   // boundary head row vals
    __shared__ float r_scr[3][WPB];

    const int tid  = threadIdx.x;
    const int lane = tid & 63;
    const int wid  = tid >> 6;
    const int colb = lane << 2;               // byte offset of lane's column

    float ht = 0.f, tt = 0.f, hh = 0.f;

    const int slice = blockIdx.x & 1;         // XCD-parity slice mapping
    const int sco   = slice << 8;             // slice*64 cols*4B
    const int chunk = (blockIdx.x >> 1) * WPB + wid;
    const int start = chunk * CPT;
    const int len   = min(CPT, total_chars - start);
    const int sl    = min(CPT + TAIL, total_chars - start);
    const char* cb  = (const char*)char_emb;
    const float* ee = ent + slice * HALF + lane;

    // ---- stage offsets + sids (wave-local region) ----
    for (int c = lane; c < sl; c += 64) {
        s_off[wid][c] = (char_ids[start + c] << 9) + sco;
        s_sid[wid][c] = seg_ids[start + c];
    }

    // ---- boundary masks (SGPR) + head-id queue (rank = prefix popcount) ----
    unsigned long long mk[4] = {0ull, 0ull, 0ull, 0ull};
    int nbq = 0;
    if (len == CPT) {
        int rbase = 0;
#pragma unroll
        for (int grp = 0; grp < 4; ++grp) {
            const int c = start + grp * 64 + lane;
            const int s1 = seg_ids[c];
            const int s0 = (c > 0) ? seg_ids[c - 1] : (s1 + 1); // char 0: boundary
            const bool bnd = (s1 != s0);
            mk[grp] = __ballot(bnd);
            const int rk = rbase + (int)__popcll(mk[grp] & ((1ull << lane) - 1ull));
            if (bnd && rk < QD) s_hq[wid][rk] = head_ids[s1];
            rbase += (int)__popcll(mk[grp]);
        }
        nbq = min(rbase, QD);

        // ---- batched pre-gather of boundary head rows (+hh fold) ----
        int r = 0;
        for (; r + 4 <= nbq; r += 4) {
            const int4 q4 = *(const int4*)&s_hq[wid][r];
            const int h0 = __builtin_amdgcn_readfirstlane(q4.x);
            const int h1 = __builtin_amdgcn_readfirstlane(q4.y);
            const int h2 = __builtin_amdgcn_readfirstlane(q4.z);
            const int h3 = __builtin_amdgcn_readfirstlane(q4.w);
            const float v0 = ee[(size_t)h0 * DIM];
            const float v1 = ee[(size_t)h1 * DIM];
            const float v2 = ee[(size_t)h2 * DIM];
            const float v3 = ee[(size_t)h3 * DIM];
            hh = fmaf(v0, v0, hh); hh = fmaf(v1, v1, hh);
            hh = fmaf(v2, v2, hh); hh = fmaf(v3, v3, hh);
            s_hv[wid][r + 0][lane] = v0;
            s_hv[wid][r + 1][lane] = v1;
            s_hv[wid][r + 2][lane] = v2;
            s_hv[wid][r + 3][lane] = v3;
        }
        for (; r < nbq; ++r) {
            const int h0 = __builtin_amdgcn_readfirstlane(s_hq[wid][r]);
            const float v0 = ee[(size_t)h0 * DIM];
            hh = fmaf(v0, v0, hh);
            s_hv[wid][r][lane] = v0;
        }
    }
    __syncthreads();

    if (len == CPT) {
        // -------- fast path --------
        int cur = (start > 0) ? seg_ids[start - 1]
                              : __builtin_amdgcn_readfirstlane(s_sid[wid][0]);
        float hv = 0.f;
        float pv = s_hv[wid][0][lane];        // pipelined boundary row value
        float acc = 0.f;
        bool live = false;      // first flush dropped iff chunk starts mid-segment
        int rk = 0;
        float vA[16], vB[16];

#define PF(BUF, B) { \
    _Pragma("unroll") \
    for (int q = 0; q < 4; ++q) { \
        const int4 o4 = *(const int4*)&s_off[wid][(B) * 16 + q * 4]; \
        BUF[q * 4 + 0] = *(const float*)(cb + (size_t)(unsigned)(o4.x + colb)); \
        BUF[q * 4 + 1] = *(const float*)(cb + (size_t)(unsigned)(o4.y + colb)); \
        BUF[q * 4 + 2] = *(const float*)(cb + (size_t)(unsigned)(o4.z + colb)); \
        BUF[q * 4 + 3] = *(const float*)(cb + (size_t)(unsigned)(o4.w + colb)); \
    } }

#define CS(BUF, B) { \
    _Pragma("unroll") \
    for (int j = 0; j < 16; ++j) { \
        if (mk[(B) >> 2] & (1ull << (((B) & 3) * 16 + j))) {   /* scalar bit test */ \
            if (live) { ht = fmaf(hv, acc, ht); tt = fmaf(acc, acc, tt); } \
            live = true; \
            acc = 0.f; \
            const int news = __builtin_amdgcn_readfirstlane(s_sid[wid][(B) * 16 + j]); \
            if (news > cur + 1) {               /* empty triples in the gap */ \
                for (int g = cur + 1; g < news; ++g) { \
                    const float gv = ee[(size_t)head_ids[g] * DIM]; \
                    hh = fmaf(gv, gv, hh); \
                } \
            } \
            cur = news; \
            if (rk < QD) {                      /* queue hit: LDS only */ \
                hv = pv; \
                const int nxt = (rk + 1 < QD) ? rk + 1 : QD - 1; \
                pv = s_hv[wid][nxt][lane]; \
            } else {                            /* rare overflow: chained */ \
                hv = ee[(size_t)head_ids[cur] * DIM]; \
                hh = fmaf(hv, hv, hh); \
            } \
            ++rk; \
        } \
        acc += BUF[j]; \
    } }

        PF(vA, 0)
#pragma unroll
        for (int B = 0; B < 16; ++B) {
            if (B + 1 < 16) { if (B & 1) { PF(vA, B + 1) } else { PF(vB, B + 1) } }
            if (B & 1) { CS(vB, B) } else { CS(vA, B) }
        }

        if (live) {
            // tail: last owned segment may continue past chunk end
            int e = CPT;
            bool ended = false;
            while (e < sl) {
                const int idx = e + lane;
                const bool differ = (idx < sl) && (s_sid[wid][idx] != cur);
                const unsigned long long bm = __ballot(differ);
                const int run = bm ? (__ffsll((long long)bm) - 1)
                                   : min(64, sl - e);
                for (int j = 0; j < run; j += 4) {
                    const int mm2 = min(4, run - j);
                    float vv[4];
#pragma unroll
                    for (int k = 0; k < 4; ++k) {
                        if (k < mm2)
                            vv[k] = *(const float*)(cb +
                                (size_t)(unsigned)(s_off[wid][e + j + k] + colb));
                    }
                    for (int k = 0; k < mm2; ++k) acc += vv[k];
                }
                e += run;
                if (bm) { ended = true; break; }
            }
            if (!ended && start + sl < total_chars) {
                int gg = start + sl;                 // very rare long run
                while (gg < total_chars && seg_ids[gg] == cur) {
                    acc += *(const float*)(cb +
                        (size_t)(unsigned)((char_ids[gg] << 9) + sco + colb));
                    ++gg;
                }
            }
            // final flush
            ht = fmaf(hv, acc, ht);
            tt = fmaf(acc, acc, tt);
        }
    } else if (len > 0) {
        // -------- rare fallback (partial last chunk): scalar per char --------
        const float* cembF = char_emb + slice * HALF + lane;
        int p = 0;
        if (start > 0) {
            const int prev = seg_ids[start - 1];
            while (p < len && seg_ids[start + p] == prev) ++p;
        }
        if (p < len) {
            int cur2 = seg_ids[start + p];
            if (start > 0) {                     // gap before first owned segment
                for (int g = seg_ids[start - 1] + 1; g < cur2; ++g) {
                    const float gv = ee[(size_t)head_ids[g] * DIM];
                    hh = fmaf(gv, gv, hh);
                }
            }
            float acc = 0.f;
            float hv = ee[(size_t)head_ids[cur2] * DIM];
            hh = fmaf(hv, hv, hh);
            for (int c = p; c < len; ++c) {
                const int sid = seg_ids[start + c];
                if (sid != cur2) {
                    ht += hv * acc; tt += acc * acc;
                    for (int g = cur2 + 1; g < sid; ++g) {   // interior gaps
                        const float gv = ee[(size_t)head_ids[g] * DIM];
                        hh = fmaf(gv, gv, hh);
                    }
                    acc = 0.f; cur2 = sid;
                    hv = ee[(size_t)head_ids[cur2] * DIM];
                    hh = fmaf(hv, hv, hh);
                }
                acc += cembF[(size_t)char_ids[start + c] * DIM];
            }
            int gg = start + len;
            while (gg < total_chars && seg_ids[gg] == cur2) {
                acc += cembF[(size_t)char_ids[gg] * DIM];
                ++gg;
            }
            ht += hv * acc; tt += acc * acc;
        }
    }

    // -------- block reduce -> per-block partials (no atomics, no memset) ----
#pragma unroll
    for (int off = 32; off > 0; off >>= 1) {
        ht += __shfl_down(ht, off);
        tt += __shfl_down(tt, off);
        hh += __shfl_down(hh, off);
    }
    if (lane == 0) { r_scr[0][wid] = ht; r_scr[1][wid] = tt; r_scr[2][wid] = hh; }
    __syncthreads();
    if (tid == 0) {
        float a = 0.f, b = 0.f, c = 0.f;
#pragma unroll
        for (int w = 0; w < WPB; ++w) {
            a += r_scr[0][w]; b += r_scr[1][w]; c += r_scr[2][w];
        }
        pb[blockIdx.x * 3 + 0] = a;
        pb[blockIdx.x * 3 + 1] = b;
        pb[blockIdx.x * 3 + 2] = c;
    }
}

// final reduce: sums partials in double, adds hh for leading/trailing empty
// triples (rows with no chars before the first / after the last seg id),
// writes N - ht/sqrt(hh*tt)
__global__ __launch_bounds__(256) void reduce_kernel(
    const float* __restrict__ pb, int nb, float* __restrict__ out,
    int n_triples, const int* __restrict__ seg_ids,
    const int* __restrict__ head_ids, const float* __restrict__ ent,
    int total_chars)
{
    double ht = 0.0, tt = 0.0, hh = 0.0;
    for (int i = threadIdx.x; i < nb; i += 256) {
        ht += (double)pb[i * 3 + 0];
        tt += (double)pb[i * 3 + 1];
        hh += (double)pb[i * 3 + 2];
    }
    // leading/trailing empty triples (typically 0-3 rows)
    int first = n_triples, last = n_triples - 1;
    if (total_chars > 0) { first = seg_ids[0]; last = seg_ids[total_chars - 1]; }
    const int lead  = first;
    const int trail = n_triples - 1 - last;
    const int tot   = lead + trail;
    const float4* e4 = (const float4*)ent;
    for (int w = threadIdx.x; w < tot * 32; w += 256) {
        const int rr = w >> 5;
        const int g  = (rr < lead) ? rr : (last + 1 + (rr - lead));
        const float4 v = e4[(size_t)head_ids[g] * 32 + (w & 31)];
        hh += (double)v.x * v.x + (double)v.y * v.y
            + (double)v.z * v.z + (double)v.w * v.w;
    }
#pragma unroll
    for (int off = 32; off > 0; off >>= 1) {
        ht += __shfl_down(ht, off);
        tt += __shfl_down(tt, off);
        hh += __shfl_down(hh, off);
    }
    __shared__ double sd[3][4];
    const int wid = threadIdx.x >> 6;
    if ((threadIdx.x & 63) == 0) { sd[0][wid] = ht; sd[1][wid] = tt; sd[2][wid] = hh; }
    __syncthreads();
    if (threadIdx.x == 0) {
        double a = 0.0, b = 0.0, c = 0.0;
        for (int w = 0; w < 4; ++w) { a += sd[0][w]; b += sd[1][w]; c += sd[2][w]; }
        out[0] = (float)((double)n_triples - a / sqrt(c * b));
    }
}

extern "C" void kernel_launch(void* const* d_in, const int* in_sizes, int n_in,
                              void* d_out, int out_size, void* d_ws, size_t ws_size,
                              hipStream_t stream)
{
    const float* char_emb = (const float*)d_in[0];
    const float* ent_emb  = (const float*)d_in[1];
    const int* head_ids   = (const int*)d_in[2];
    const int* char_ids   = (const int*)d_in[3];
    const int* seg_ids    = (const int*)d_in[4];
    const int n_triples   = in_sizes[2];
    const int total_chars = in_sizes[3];

    const int n_chunks = (total_chars + CPT - 1) / CPT;
    const int bps = (n_chunks + WPB - 1) / WPB;
    const int nsb = (2 * bps > 0) ? 2 * bps : 2;   // x2 slices

    float* pb = (float*)d_ws;                      // nsb*3 floats

    fused_kernel<<<nsb, 256, 0, stream>>>(char_emb, ent_emb, head_ids,
                                          char_ids, seg_ids, pb,
                                          total_chars, n_triples);
    reduce_kernel<<<1, 256, 0, stream>>>(pb, nsb, (float*)d_out, n_triples,
                                         seg_ids, head_ids, ent_emb,
                                         total_chars);
}

// Round 3
// 178.528 us; speedup vs baseline: 1.0554x; 1.0457x over previous
//
#include <hip/hip_runtime.h>

#define DIM   128
#define HALF  64          // columns per slice (2 slices, XCD-parity L2 residency)
#define CPT   256         // chars per wave-chunk
#define TAIL  64          // staged lookahead for cross-chunk tails
#define WPB   4           // waves per block
#define QD    32          // boundary id queue depth (Poisson(16); overflow->chained)

// out = N - <H,T>_F / (||H||_F ||T||_F).  T never materialized; hh folded into
// the boundary events (each non-empty segment starts in exactly one chunk),
// empty segments via ballot'd gap loop + reduce-kernel ends.
// Wave layout: lane = column of the 64-col slice; all lanes process the SAME
// char together -> wave-uniform control flow. Boundary masks in SGPRs (scalar
// bit test per char). Boundary head *ids* pre-gathered to a tiny LDS queue;
// head row *values* flow through a 4-deep register pipeline (r0..r3) so each
// row load is issued ~4 segment-intervals before its use -> no exposed VMEM
// chain at boundaries and no occupancy cost (LDS stays ~11 KB).
__global__ __launch_bounds__(256) void fused_kernel(
    const float* __restrict__ char_emb,
    const float* __restrict__ ent,
    const int* __restrict__ head_ids,
    const int* __restrict__ char_ids,
    const int* __restrict__ seg_ids,
    float* __restrict__ pb,        // [gridDim.x*3] block partials: ht,tt,hh
    int total_chars, int n_triples)
{
    __shared__ __align__(16) int s_off[WPB][CPT + TAIL];  // (cid<<9)+sco
    __shared__ int s_sid[WPB][CPT + TAIL];
    __shared__ int s_hq[WPB][QD];                         // boundary head ids
    __shared__ float r_scr[3][WPB];

    const int tid  = threadIdx.x;
    const int lane = tid & 63;
    const int wid  = tid >> 6;
    const int colb = lane << 2;               // byte offset of lane's column

    float ht = 0.f, tt = 0.f, hh = 0.f;

    const int slice = blockIdx.x & 1;         // XCD-parity slice mapping
    const int sco   = slice << 8;             // slice*64 cols*4B
    const int chunk = (blockIdx.x >> 1) * WPB + wid;
    const int start = chunk * CPT;
    const int len   = min(CPT, total_chars - start);
    const int sl    = min(CPT + TAIL, total_chars - start);
    const char* cb  = (const char*)char_emb;
    const float* ee = ent + slice * HALF + lane;

    // ---- stage offsets + sids (wave-private region; no barrier needed) ----
    for (int c = lane; c < sl; c += 64) {
        s_off[wid][c] = (char_ids[start + c] << 9) + sco;
        s_sid[wid][c] = seg_ids[start + c];
    }

    // ---- boundary masks (SGPR) + id queue + gap-hh (all off critical path) --
    unsigned long long mk[4] = {0ull, 0ull, 0ull, 0ull};
    int nbq = 0;
    if (len == CPT) {
        int rbase = 0;
#pragma unroll
        for (int grp = 0; grp < 4; ++grp) {
            const int c = start + grp * 64 + lane;
            const int s1 = seg_ids[c];
            const int s0 = (c > 0) ? seg_ids[c - 1] : (s1 + 1); // char 0: boundary
            const bool bnd = (s1 != s0);
            mk[grp] = __ballot(bnd);
            const int rk0 = rbase + (int)__popcll(mk[grp] & ((1ull << lane) - 1ull));
            if (bnd && rk0 < QD) s_hq[wid][rk0] = head_ids[s1];
            rbase += (int)__popcll(mk[grp]);
            // empty triples between s0 and s1: statistically never taken
            unsigned long long gapm = __ballot(s1 > s0 + 1);
            while (gapm) {
                const int l  = __ffsll((long long)gapm) - 1;
                const int g0 = __shfl(s0, l);
                const int g1 = __shfl(s1, l);
                for (int g = g0 + 1; g < g1; ++g) {
                    const float gv = ee[(size_t)head_ids[g] * DIM];
                    hh = fmaf(gv, gv, hh);
                }
                gapm &= gapm - 1;
            }
        }
        nbq = min(rbase, QD);
    }

    if (len == CPT) {
        // -------- fast path --------
        float hv = 0.f;
        float acc = 0.f;
        bool live = false;      // first flush dropped iff chunk starts mid-segment
        int rk = 0;
        // 4-deep register pipeline of boundary head-row values
        float r0 = 0.f, r1 = 0.f, r2 = 0.f, r3 = 0.f;
        if (nbq > 0) r0 = ee[(size_t)__builtin_amdgcn_readfirstlane(s_hq[wid][0]) * DIM];
        if (nbq > 1) r1 = ee[(size_t)__builtin_amdgcn_readfirstlane(s_hq[wid][1]) * DIM];
        if (nbq > 2) r2 = ee[(size_t)__builtin_amdgcn_readfirstlane(s_hq[wid][2]) * DIM];
        if (nbq > 3) r3 = ee[(size_t)__builtin_amdgcn_readfirstlane(s_hq[wid][3]) * DIM];
        float vA[16], vB[16];

#define PF(BUF, B) { \
    _Pragma("unroll") \
    for (int q = 0; q < 4; ++q) { \
        const int4 o4 = *(const int4*)&s_off[wid][(B) * 16 + q * 4]; \
        BUF[q * 4 + 0] = *(const float*)(cb + (size_t)(unsigned)(o4.x + colb)); \
        BUF[q * 4 + 1] = *(const float*)(cb + (size_t)(unsigned)(o4.y + colb)); \
        BUF[q * 4 + 2] = *(const float*)(cb + (size_t)(unsigned)(o4.z + colb)); \
        BUF[q * 4 + 3] = *(const float*)(cb + (size_t)(unsigned)(o4.w + colb)); \
    } }

#define CS(BUF, B) { \
    _Pragma("unroll") \
    for (int j = 0; j < 16; ++j) { \
        if (mk[(B) >> 2] & (1ull << (((B) & 3) * 16 + j))) {   /* scalar bit test */ \
            if (live) { ht = fmaf(hv, acc, ht); tt = fmaf(acc, acc, tt); } \
            live = true; \
            acc = 0.f; \
            if (rk < QD) {                      /* pipeline hit: no chase */ \
                hv = r0; r0 = r1; r1 = r2; r2 = r3; \
                const int ni = rk + 4; \
                r3 = (ni < nbq) \
                   ? ee[(size_t)__builtin_amdgcn_readfirstlane(s_hq[wid][ni]) * DIM] \
                   : 0.f; \
            } else {                            /* rare overflow: chained */ \
                const int cs = __builtin_amdgcn_readfirstlane(s_sid[wid][(B) * 16 + j]); \
                hv = ee[(size_t)head_ids[cs] * DIM]; \
            } \
            hh = fmaf(hv, hv, hh);              /* boundary event: fold ||h||^2 */ \
            ++rk; \
        } \
        acc += BUF[j]; \
    } }

        PF(vA, 0)
#pragma unroll
        for (int B = 0; B < 16; ++B) {
            if (B + 1 < 16) { if (B & 1) { PF(vA, B + 1) } else { PF(vB, B + 1) } }
            if (B & 1) { CS(vB, B) } else { CS(vA, B) }
        }

        if (live) {
            // tail: last owned segment may continue past chunk end
            int cur = __builtin_amdgcn_readfirstlane(s_sid[wid][CPT - 1]);
            int e = CPT;
            bool ended = false;
            while (e < sl) {
                const int idx = e + lane;
                const bool differ = (idx < sl) && (s_sid[wid][idx] != cur);
                const unsigned long long bm = __ballot(differ);
                const int run = bm ? (__ffsll((long long)bm) - 1)
                                   : min(64, sl - e);
                for (int j = 0; j < run; j += 4) {
                    const int mm2 = min(4, run - j);
                    float vv[4];
#pragma unroll
                    for (int k = 0; k < 4; ++k) {
                        if (k < mm2)
                            vv[k] = *(const float*)(cb +
                                (size_t)(unsigned)(s_off[wid][e + j + k] + colb));
                    }
                    for (int k = 0; k < mm2; ++k) acc += vv[k];
                }
                e += run;
                if (bm) { ended = true; break; }
            }
            if (!ended && start + sl < total_chars) {
                int gg = start + sl;                 // very rare long run
                while (gg < total_chars && seg_ids[gg] == cur) {
                    acc += *(const float*)(cb +
                        (size_t)(unsigned)((char_ids[gg] << 9) + sco + colb));
                    ++gg;
                }
            }
            // final flush
            ht = fmaf(hv, acc, ht);
            tt = fmaf(acc, acc, tt);
        }
    } else if (len > 0) {
        // -------- rare fallback (partial last chunk): scalar per char --------
        const float* cembF = char_emb + slice * HALF + lane;
        int p = 0;
        if (start > 0) {
            const int prev = seg_ids[start - 1];
            while (p < len && seg_ids[start + p] == prev) ++p;
        }
        if (p < len) {
            int cur2 = seg_ids[start + p];
            if (start > 0) {                     // gap before first owned segment
                for (int g = seg_ids[start - 1] + 1; g < cur2; ++g) {
                    const float gv = ee[(size_t)head_ids[g] * DIM];
                    hh = fmaf(gv, gv, hh);
                }
            }
            float acc = 0.f;
            float hv = ee[(size_t)head_ids[cur2] * DIM];
            hh = fmaf(hv, hv, hh);
            for (int c = p; c < len; ++c) {
                const int sid = seg_ids[start + c];
                if (sid != cur2) {
                    ht += hv * acc; tt += acc * acc;
                    for (int g = cur2 + 1; g < sid; ++g) {   // interior gaps
                        const float gv = ee[(size_t)head_ids[g] * DIM];
                        hh = fmaf(gv, gv, hh);
                    }
                    acc = 0.f; cur2 = sid;
                    hv = ee[(size_t)head_ids[cur2] * DIM];
                    hh = fmaf(hv, hv, hh);
                }
                acc += cembF[(size_t)char_ids[start + c] * DIM];
            }
            int gg = start + len;
            while (gg < total_chars && seg_ids[gg] == cur2) {
                acc += cembF[(size_t)char_ids[gg] * DIM];
                ++gg;
            }
            ht += hv * acc; tt += acc * acc;
        }
    }

    // -------- block reduce -> per-block partials (no atomics, no memset) ----
#pragma unroll
    for (int off = 32; off > 0; off >>= 1) {
        ht += __shfl_down(ht, off);
        tt += __shfl_down(tt, off);
        hh += __shfl_down(hh, off);
    }
    if (lane == 0) { r_scr[0][wid] = ht; r_scr[1][wid] = tt; r_scr[2][wid] = hh; }
    __syncthreads();
    if (tid == 0) {
        float a = 0.f, b = 0.f, c = 0.f;
#pragma unroll
        for (int w = 0; w < WPB; ++w) {
            a += r_scr[0][w]; b += r_scr[1][w]; c += r_scr[2][w];
        }
        pb[blockIdx.x * 3 + 0] = a;
        pb[blockIdx.x * 3 + 1] = b;
        pb[blockIdx.x * 3 + 2] = c;
    }
}

// final reduce: sums partials in double, adds hh for leading/trailing empty
// triples (rows with no chars before the first / after the last seg id),
// writes N - ht/sqrt(hh*tt)
__global__ __launch_bounds__(256) void reduce_kernel(
    const float* __restrict__ pb, int nb, float* __restrict__ out,
    int n_triples, const int* __restrict__ seg_ids,
    const int* __restrict__ head_ids, const float* __restrict__ ent,
    int total_chars)
{
    double ht = 0.0, tt = 0.0, hh = 0.0;
    for (int i = threadIdx.x; i < nb; i += 256) {
        ht += (double)pb[i * 3 + 0];
        tt += (double)pb[i * 3 + 1];
        hh += (double)pb[i * 3 + 2];
    }
    // leading/trailing empty triples (typically 0-3 rows)
    int first = n_triples, last = n_triples - 1;
    if (total_chars > 0) { first = seg_ids[0]; last = seg_ids[total_chars - 1]; }
    const int lead  = first;
    const int trail = n_triples - 1 - last;
    const int tot   = lead + trail;
    const float4* e4 = (const float4*)ent;
    for (int w = threadIdx.x; w < tot * 32; w += 256) {
        const int rr = w >> 5;
        const int g  = (rr < lead) ? rr : (last + 1 + (rr - lead));
        const float4 v = e4[(size_t)head_ids[g] * 32 + (w & 31)];
        hh += (double)v.x * v.x + (double)v.y * v.y
            + (double)v.z * v.z + (double)v.w * v.w;
    }
#pragma unroll
    for (int off = 32; off > 0; off >>= 1) {
        ht += __shfl_down(ht, off);
        tt += __shfl_down(tt, off);
        hh += __shfl_down(hh, off);
    }
    __shared__ double sd[3][4];
    const int wid = threadIdx.x >> 6;
    if ((threadIdx.x & 63) == 0) { sd[0][wid] = ht; sd[1][wid] = tt; sd[2][wid] = hh; }
    __syncthreads();
    if (threadIdx.x == 0) {
        double a = 0.0, b = 0.0, c = 0.0;
        for (int w = 0; w < 4; ++w) { a += sd[0][w]; b += sd[1][w]; c += sd[2][w]; }
        out[0] = (float)((double)n_triples - a / sqrt(c * b));
    }
}

extern "C" void kernel_launch(void* const* d_in, const int* in_sizes, int n_in,
                              void* d_out, int out_size, void* d_ws, size_t ws_size,
                              hipStream_t stream)
{
    const float* char_emb = (const float*)d_in[0];
    const float* ent_emb  = (const float*)d_in[1];
    const int* head_ids   = (const int*)d_in[2];
    const int* char_ids   = (const int*)d_in[3];
    const int* seg_ids    = (const int*)d_in[4];
    const int n_triples   = in_sizes[2];
    const int total_chars = in_sizes[3];

    const int n_chunks = (total_chars + CPT - 1) / CPT;
    const int bps = (n_chunks + WPB - 1) / WPB;
    const int nsb = (2 * bps > 0) ? 2 * bps : 2;   // x2 slices

    float* pb = (float*)d_ws;                      // nsb*3 floats

    fused_kernel<<<nsb, 256, 0, stream>>>(char_emb, ent_emb, head_ids,
                                          char_ids, seg_ids, pb,
                                          total_chars, n_triples);
    reduce_kernel<<<1, 256, 0, stream>>>(pb, nsb, (float*)d_out, n_triples,
                                         seg_ids, head_ids, ent_emb,
                                         total_chars);
}